// Round 5
// baseline (154.230 us; speedup 1.0000x reference)
//
#include <hip/hip_runtime.h>
#include <hip/hip_bf16.h>

typedef __bf16 bf16;
typedef __bf16 bf16x4 __attribute__((ext_vector_type(4)));
typedef __bf16 bf16x8 __attribute__((ext_vector_type(8)));
typedef float  floatx4 __attribute__((ext_vector_type(4)));

#define D_MODEL   1024
#define NUM_HEADS 16
#define NUM_GROUPS 4
#define DK        64
#define SEQ_T     2048
#define BATCH     2
#define M_ROWS    (BATCH*SEQ_T)   // 4096
#define WINDOW    512
#define KV_DIM    (NUM_GROUPS*DK) // 256
#define N_QKV     (D_MODEL + 2*KV_DIM)  // 1536
#define KDIM      1024
// Q pre-scale: 1/sqrt(64) * log2(e)  (exp -> exp2 domain)
#define QSCALE    0.1803368801111204f
// log2(10000)/32
#define FREQ_C    0.4152410118609203f

static __device__ __forceinline__ bf16x8 cv8(float4 a, float4 b)
{
    bf16x8 v;
    v[0] = (bf16)a.x; v[1] = (bf16)a.y; v[2] = (bf16)a.z; v[3] = (bf16)a.w;
    v[4] = (bf16)b.x; v[5] = (bf16)b.y; v[6] = (bf16)b.z; v[7] = (bf16)b.w;
    return v;
}

// ---------------------------------------------------------------------------
// bf16-compute GEMM from fp32 sources, C = A @ W^T. 128x64 tile, 4 waves each
// 64x32 (4x2 acc), BK=64. Reg-staged fp32->bf16 (convert pass deleted):
// thread loads 2x float4 per chunk, converts, ds_write_b128 into the T2
// XOR-swizzled slot (identical layout to the proven glds scheme; read side
// unchanged, conflict-free). 2-phase double buffer: load next tile to regs
// during current tile's MFMA; one barrier per K-step. LDS 48 KB -> 3 blk/CU.
// mode 0: W = {W0=WQ, W1=WK, W2=WV} segments; Q/K rope epilogue, V transpose.
// mode 1: W = {W0=WO}; fp32 output Co.
// ---------------------------------------------------------------------------
__global__ __launch_bounds__(256, 3)
void gemm_t64(const float* __restrict__ A,
              const float* __restrict__ W0, const float* __restrict__ W1,
              const float* __restrict__ W2,
              bf16* __restrict__ Cq, bf16* __restrict__ Ck,
              bf16* __restrict__ Vt, float* __restrict__ Co,
              const int* __restrict__ pos, int mode)
{
    __shared__ bf16 As[2][128 * 64];   // 16 KB per buffer
    __shared__ bf16 Bs[2][64 * 64];    //  8 KB per buffer

    const int tid  = threadIdx.x;
    const int wave = tid >> 6;
    const int lane = tid & 63;
    const int lr   = lane & 15;
    const int quad = lane >> 4;
    const int m0 = blockIdx.y * 128;
    const int n0 = blockIdx.x * 64;
    const int wm = (wave >> 1) * 64;
    const int wn = (wave & 1) * 32;

    // W segment select (boundaries 64-aligned; whole 64-row tile inside one)
    const float* Wseg; int wrow;
    if      (n0 < D_MODEL)          { Wseg = W0; wrow = n0; }
    else if (n0 < D_MODEL + KV_DIM) { Wseg = W1; wrow = n0 - D_MODEL; }
    else                            { Wseg = W2; wrow = n0 - D_MODEL - KV_DIM; }

    // ---- staging geometry (swizzled slot; same layout as proven glds) ----
    const int cr8 = lane >> 3;                       // row within 8-row chunk
    const int cc  = ((lane & 7) ^ cr8) * 8;          // swizzled col (elems)
    const float* Ag = &A[(size_t)(m0 + cr8) * KDIM + cc];
    const float* Wg = &Wseg[(size_t)(wrow + cr8) * KDIM + cc];

    float4 ra[6][2];
#define LOADT(kk)                                                             \
    do {                                                                      \
        _Pragma("unroll")                                                     \
        for (int c = 0; c < 4; c++) {                                         \
            const float* p = Ag + (size_t)((wave * 4 + c) * 8) * KDIM + (kk); \
            ra[c][0] = *(const float4*)p;                                     \
            ra[c][1] = *(const float4*)(p + 4);                               \
        }                                                                     \
        _Pragma("unroll")                                                     \
        for (int c = 0; c < 2; c++) {                                         \
            const float* p = Wg + (size_t)((wave * 2 + c) * 8) * KDIM + (kk); \
            ra[4 + c][0] = *(const float4*)p;                                 \
            ra[4 + c][1] = *(const float4*)(p + 4);                           \
        }                                                                     \
    } while (0)

#define CVTW(buf)                                                             \
    do {                                                                      \
        _Pragma("unroll")                                                     \
        for (int c = 0; c < 4; c++)                                           \
            *(bf16x8*)&As[buf][(wave * 4 + c) * 512 + lane * 8] =             \
                cv8(ra[c][0], ra[c][1]);                                      \
        _Pragma("unroll")                                                     \
        for (int c = 0; c < 2; c++)                                           \
            *(bf16x8*)&Bs[buf][(wave * 2 + c) * 512 + lane * 8] =             \
                cv8(ra[4 + c][0], ra[4 + c][1]);                              \
    } while (0)

    // ---- fragment-read swizzled column offsets (lane-constant) ----
    const int ax0 = (quad ^ (lane & 7)) * 8;         // ks=0 col offset (elems)
    const int ax1 = ax0 ^ 32;                        // ks=1: col16 ^= 4

    floatx4 acc[4][2];
#pragma unroll
    for (int i = 0; i < 4; i++)
#pragma unroll
        for (int j = 0; j < 2; j++) acc[i][j] = (floatx4)(0.0f);

    // prologue: stage tile 0
    LOADT(0);
    CVTW(0);
    __syncthreads();

    int cur = 0;
    for (int k0 = 0; k0 < KDIM; k0 += 64) {
        const bool nxt = (k0 + 64 < KDIM);
        if (nxt) LOADT(k0 + 64);     // issue next-tile global loads early

        bf16x8 a0[4], a1[4], b0[2], b1[2];
#pragma unroll
        for (int mi = 0; mi < 4; mi++) {
            a0[mi] = *(const bf16x8*)&As[cur][(wm + mi * 16 + lr) * 64 + ax0];
            a1[mi] = *(const bf16x8*)&As[cur][(wm + mi * 16 + lr) * 64 + ax1];
        }
#pragma unroll
        for (int ni = 0; ni < 2; ni++) {
            b0[ni] = *(const bf16x8*)&Bs[cur][(wn + ni * 16 + lr) * 64 + ax0];
            b1[ni] = *(const bf16x8*)&Bs[cur][(wn + ni * 16 + lr) * 64 + ax1];
        }

#pragma unroll
        for (int mi = 0; mi < 4; mi++)
#pragma unroll
            for (int ni = 0; ni < 2; ni++) {
                acc[mi][ni] = __builtin_amdgcn_mfma_f32_16x16x32_bf16(
                    a0[mi], b0[ni], acc[mi][ni], 0, 0, 0);
                acc[mi][ni] = __builtin_amdgcn_mfma_f32_16x16x32_bf16(
                    a1[mi], b1[ni], acc[mi][ni], 0, 0, 0);
            }

        if (nxt) CVTW(cur ^ 1);      // cvt + ds_write next tile (other buffer)
        __syncthreads();             // writes visible; prev reads done
        cur ^= 1;
    }
#undef LOADT
#undef CVTW

    if (mode == 0) {
        if (n0 >= D_MODEL + KV_DIM) {
            // ---- V: store transposed into Vt[(bg*64+d)*SEQ_T + t] ----
            const int g  = (n0 - (D_MODEL + KV_DIM)) >> 6;   // 0..3
            const int b  = m0 >> 11;
            const int bg = b * 4 + g;
#pragma unroll
            for (int mi = 0; mi < 4; mi++) {
#pragma unroll
                for (int ni = 0; ni < 2; ni++) {
                    int d  = wn + ni * 16 + lr;
                    int t0 = (m0 & (SEQ_T - 1)) + wm + mi * 16 + quad * 4;
                    bf16x4 v;
#pragma unroll
                    for (int r = 0; r < 4; r++) v[r] = (bf16)acc[mi][ni][r];
                    *(bf16x4*)&Vt[((size_t)(bg * 64 + d)) * SEQ_T + t0] = v;
                }
            }
        } else {
            // ---- Q / K: RoPE epilogue ----
            bf16* out; int ld, coff; float sc;
            if (n0 < D_MODEL) { out = Cq; ld = D_MODEL; coff = n0; sc = QSCALE; }
            else              { out = Ck; ld = KV_DIM;  coff = n0 - D_MODEL; sc = 1.0f; }
            float inv[2];
            float sgn = (lr & 1) ? 1.0f : -1.0f;
#pragma unroll
            for (int ni = 0; ni < 2; ni++) {
                int ip = (wn + ni * 16 + lr) >> 1;      // pair index 0..31 within head
                inv[ni] = exp2f(-(float)ip * FREQ_C);
            }
#pragma unroll
            for (int mi = 0; mi < 4; mi++) {
#pragma unroll
                for (int r = 0; r < 4; r++) {
                    int row = m0 + wm + mi * 16 + quad * 4 + r;
                    float p = (float)pos[row & (SEQ_T - 1)];
#pragma unroll
                    for (int ni = 0; ni < 2; ni++) {
                        float v  = acc[mi][ni][r];
                        float vp = __shfl_xor(v, 1);
                        float ang = p * inv[ni];
                        float ss, cc2;
                        __sincosf(ang, &ss, &cc2);
                        v = v * cc2 + vp * ss * sgn;    // even: x1 c - x2 s ; odd: x1 s + x2 c
                        out[(size_t)row * ld + coff + wn + ni * 16 + lr] = (bf16)(v * sc);
                    }
                }
            }
        }
    } else {
#pragma unroll
        for (int mi = 0; mi < 4; mi++)
#pragma unroll
            for (int ni = 0; ni < 2; ni++)
#pragma unroll
                for (int r = 0; r < 4; r++) {
                    int row = m0 + wm + mi * 16 + quad * 4 + r;
                    int col = n0 + wn + ni * 16 + lr;
                    Co[(size_t)row * D_MODEL + col] = acc[mi][ni][r];
                }
    }
}

// ---------------------------------------------------------------------------
// GQA-fused MFMA flash attention, P-in-register + T14 async staging.
//   Swapped QK^T (mfma(kf,qf) -> S^T, P lane-local); key-permuted PV.
//   K/V tiles for step j0+64 are prefetched into registers right after the
//   current tile's LDS write, so global latency hides under QK/softmax/PV.
//   AO output is fp32 (feeds fp32-staged O-proj). LDS 20.7 KB.
// ---------------------------------------------------------------------------
__global__ __launch_bounds__(256, 3)
void attn_mfma(const bf16* __restrict__ Q, const bf16* __restrict__ K,
               const bf16* __restrict__ Vt_g, float* __restrict__ AO)
{
    const int ST = 72;
    __shared__ bf16 Ks[64 * ST];
    __shared__ bf16 Vt[80 * ST];        // row 64 = ones, 65-79 zeros

    const int tid  = threadIdx.x;
    const int wave = tid >> 6;
    const int lane = tid & 63;
    const int lr   = lane & 15;
    const int quad = lane >> 4;
    const int bg = blockIdx.y;
    const int b = bg >> 2, g = bg & 3;
    const int h = g * 4 + wave;
    const int q0 = blockIdx.x * 32;

    bf16x8 qf[2][2];
#pragma unroll
    for (int mi = 0; mi < 2; mi++)
#pragma unroll
        for (int ks = 0; ks < 2; ks++)
            qf[mi][ks] = *(const bf16x8*)
                &Q[((size_t)(b * SEQ_T + q0 + mi * 16 + lr)) * D_MODEL
                   + h * 64 + ks * 32 + quad * 8];

    for (int i = tid; i < 15 * ST; i += 256) Vt[65 * ST + i] = (bf16)0.0f;
    if (tid < ST) Vt[64 * ST + tid] = (bf16)(tid < 64 ? 1.0f : 0.0f);

    floatx4 o[2][5];
#pragma unroll
    for (int mi = 0; mi < 2; mi++)
#pragma unroll
        for (int nt = 0; nt < 5; nt++) o[mi][nt] = (floatx4)(0.0f);

    const int t0   = (q0 >= WINDOW) ? ((q0 - WINDOW) & ~63) : 0;
    const int last = q0 & ~63;

    // per-thread staging slots: i=0,1 -> c = tid + i*256, row c>>3, col (c&7)*8
    const int srow0 = tid >> 3,        scol0 = (tid & 7) * 8;
    const int srow1 = (tid + 256) >> 3, scol1 = ((tid + 256) & 7) * 8;

    bf16x8 kreg[2], vreg[2];
#define LOADKV(jn)                                                            \
    do {                                                                      \
        kreg[0] = *(const bf16x8*)&K[((size_t)(b * SEQ_T + (jn) + srow0)) * KV_DIM + g * 64 + scol0]; \
        vreg[0] = *(const bf16x8*)&Vt_g[((size_t)(bg * 64 + srow0)) * SEQ_T + (jn) + scol0];          \
        kreg[1] = *(const bf16x8*)&K[((size_t)(b * SEQ_T + (jn) + srow1)) * KV_DIM + g * 64 + scol1]; \
        vreg[1] = *(const bf16x8*)&Vt_g[((size_t)(bg * 64 + srow1)) * SEQ_T + (jn) + scol1];          \
    } while (0)

    LOADKV(t0);

    for (int j0 = t0; j0 <= last; j0 += 64) {
        const bool mC = (j0 == last);
        const bool mW = (q0 >= WINDOW) && (j0 == t0);
        __syncthreads();                      // prev compute done with LDS
        *(bf16x8*)&Ks[srow0 * ST + scol0] = kreg[0];
        *(bf16x8*)&Vt[srow0 * ST + scol0] = vreg[0];
        *(bf16x8*)&Ks[srow1 * ST + scol1] = kreg[1];
        *(bf16x8*)&Vt[srow1 * ST + scol1] = vreg[1];
        if (j0 + 64 <= last) LOADKV(j0 + 64); // prefetch next tile into regs
        __syncthreads();                      // LDS tile ready

        // ---- QK^T swapped: lane holds S[key=nt*16+quad*4+r][q=mi*16+lr] ----
        floatx4 s2[4][2];
#pragma unroll
        for (int nt = 0; nt < 4; nt++)
#pragma unroll
            for (int mi = 0; mi < 2; mi++) s2[nt][mi] = (floatx4)(0.0f);
#pragma unroll
        for (int ks = 0; ks < 2; ks++) {
#pragma unroll
            for (int nt = 0; nt < 4; nt++) {
                bf16x8 kf = *(const bf16x8*)&Ks[(nt * 16 + lr) * ST + ks * 32 + quad * 8];
                s2[nt][0] = __builtin_amdgcn_mfma_f32_16x16x32_bf16(kf, qf[0][ks], s2[nt][0], 0, 0, 0);
                s2[nt][1] = __builtin_amdgcn_mfma_f32_16x16x32_bf16(kf, qf[1][ks], s2[nt][1], 0, 0, 0);
            }
        }

        if (mC) {
#pragma unroll
            for (int nt = 0; nt < 4; nt++)
#pragma unroll
                for (int mi = 0; mi < 2; mi++) {
                    int qi_ = q0 + mi * 16 + lr;
#pragma unroll
                    for (int r = 0; r < 4; r++) {
                        int key = j0 + nt * 16 + quad * 4 + r;
                        s2[nt][mi][r] = (key <= qi_) ? s2[nt][mi][r] : -1e30f;
                    }
                }
        } else if (mW) {
#pragma unroll
            for (int nt = 0; nt < 4; nt++)
#pragma unroll
                for (int mi = 0; mi < 2; mi++) {
                    int qi_ = q0 + mi * 16 + lr;
#pragma unroll
                    for (int r = 0; r < 4; r++) {
                        int key = j0 + nt * 16 + quad * 4 + r;
                        s2[nt][mi][r] = (qi_ - key <= WINDOW) ? s2[nt][mi][r] : -1e30f;
                    }
                }
        }

        // ---- exp2 + lane-local pack into key-permuted A-frags ----
        bf16x8 pa[2][2];
#pragma unroll
        for (int mi = 0; mi < 2; mi++)
#pragma unroll
            for (int ks = 0; ks < 2; ks++)
#pragma unroll
                for (int r = 0; r < 4; r++) {
                    pa[mi][ks][r]     = (bf16)exp2f(s2[2 * ks][mi][r]);
                    pa[mi][ks][r + 4] = (bf16)exp2f(s2[2 * ks + 1][mi][r]);
                }

        // ---- PV with key-permuted B-frag (two b64 reads per vf) ----
#pragma unroll
        for (int ks = 0; ks < 2; ks++) {
#pragma unroll
            for (int nt = 0; nt < 5; nt++) {
                const bf16* vb = &Vt[(nt * 16 + lr) * ST + ks * 32 + quad * 4];
                bf16x4 vlo = *(const bf16x4*)vb;
                bf16x4 vhi = *(const bf16x4*)(vb + 16);
                bf16x8 vf = __builtin_shufflevector(vlo, vhi, 0, 1, 2, 3, 4, 5, 6, 7);
                o[0][nt] = __builtin_amdgcn_mfma_f32_16x16x32_bf16(pa[0][ks], vf, o[0][nt], 0, 0, 0);
                o[1][nt] = __builtin_amdgcn_mfma_f32_16x16x32_bf16(pa[1][ks], vf, o[1][nt], 0, 0, 0);
            }
        }
    }
#undef LOADKV

#pragma unroll
    for (int mi = 0; mi < 2; mi++)
#pragma unroll
        for (int r = 0; r < 4; r++) {
            float l = __shfl(o[mi][4][r], lane & 48);
            float invl = 1.0f / l;
            int row = q0 + mi * 16 + quad * 4 + r;
#pragma unroll
            for (int nt = 0; nt < 4; nt++)
                AO[((size_t)(b * SEQ_T + row)) * D_MODEL + h * 64 + nt * 16 + lr] =
                    o[mi][nt][r] * invl;
        }
}

// ---------------------------------------------------------------------------
extern "C" void kernel_launch(void* const* d_in, const int* in_sizes, int n_in,
                              void* d_out, int out_size, void* d_ws, size_t ws_size,
                              hipStream_t stream)
{
    const float* x  = (const float*)d_in[0];
    const float* WQ = (const float*)d_in[1];
    const float* WK = (const float*)d_in[2];
    const float* WV = (const float*)d_in[3];
    const float* WO = (const float*)d_in[4];
    const int*  pos = (const int*)d_in[5];

    // ws: Qw 8MB | Kw 2MB | Vt_g 2MB | AO fp32 16MB
    char* ws    = (char*)d_ws;
    bf16* Qw    = (bf16*)ws;
    bf16* Kw    = (bf16*)(ws + (size_t) 8 * 1024 * 1024);
    bf16* Vt_g  = (bf16*)(ws + (size_t)10 * 1024 * 1024);
    float* AOf  = (float*)(ws + (size_t)12 * 1024 * 1024);

    // fused QKV projection (fp32 sources) + RoPE epilogue + V-transpose
    gemm_t64<<<dim3(N_QKV / 64, M_ROWS / 128), 256, 0, stream>>>(
        x, WQ, WK, WV, Qw, Kw, Vt_g, nullptr, pos, 0);

    // GQA-fused attention (fp32 AO out)
    attn_mfma<<<dim3(SEQ_T / 32, BATCH * NUM_GROUPS), 256, 0, stream>>>(
        Qw, Kw, Vt_g, AOf);

    // output projection -> fp32 d_out
    gemm_t64<<<dim3(D_MODEL / 64, M_ROWS / 128), 256, 0, stream>>>(
        AOf, WO, nullptr, nullptr, nullptr, nullptr, nullptr,
        (float*)d_out, pos, 1);
}

// Round 6
// 151.271 us; speedup vs baseline: 1.0196x; 1.0196x over previous
//
#include <hip/hip_runtime.h>
#include <hip/hip_bf16.h>

typedef __bf16 bf16;
typedef __bf16 bf16x4 __attribute__((ext_vector_type(4)));
typedef __bf16 bf16x8 __attribute__((ext_vector_type(8)));
typedef float  floatx4 __attribute__((ext_vector_type(4)));

#define D_MODEL   1024
#define NUM_HEADS 16
#define NUM_GROUPS 4
#define DK        64
#define SEQ_T     2048
#define BATCH     2
#define M_ROWS    (BATCH*SEQ_T)   // 4096
#define WINDOW    512
#define KV_DIM    (NUM_GROUPS*DK) // 256
#define N_QKV     (D_MODEL + 2*KV_DIM)  // 1536
#define KDIM      1024
// Q pre-scale: 1/sqrt(64) * log2(e)  (exp -> exp2 domain)
#define QSCALE    0.1803368801111204f
// log2(10000)/32
#define FREQ_C    0.4152410118609203f

static __device__ __forceinline__ bf16x8 cv8(float4 a, float4 b)
{
    bf16x8 v;
    v[0] = (bf16)a.x; v[1] = (bf16)a.y; v[2] = (bf16)a.z; v[3] = (bf16)a.w;
    v[4] = (bf16)b.x; v[5] = (bf16)b.y; v[6] = (bf16)b.z; v[7] = (bf16)b.w;
    return v;
}

// ---------------------------------------------------------------------------
// bf16-compute GEMM from fp32 sources, C = A @ W^T. 128x64 tile, 4 waves each
// 64x32 (4x2 acc), BK=64. Reg-staged fp32->bf16; T2 XOR-swizzled LDS;
// 2-phase double buffer.
// T1 XCD swizzle (R5): 1-D grid, xcd = bid&7 owns a contiguous v-range.
// nwg/8 is an exact multiple of NX (96=4*24, 64=4*16), so each XCD owns 4
// M-panels EXCLUSIVELY and sweeps each panel's N-tiles back-to-back -> every
// fp32 A-panel (512 KB) is fetched into exactly one XCD L2, once.
// mode 0: W = {W0=WQ, W1=WK, W2=WV} segments; Q/K rope epilogue, V transpose.
// mode 1: W = {W0=WO}; fp32 output Co.
// ---------------------------------------------------------------------------
__global__ __launch_bounds__(256, 3)
void gemm_t64(const float* __restrict__ A,
              const float* __restrict__ W0, const float* __restrict__ W1,
              const float* __restrict__ W2,
              bf16* __restrict__ Cq, bf16* __restrict__ Ck,
              bf16* __restrict__ Vt, float* __restrict__ Co,
              const int* __restrict__ pos, int mode)
{
    __shared__ bf16 As[2][128 * 64];   // 16 KB per buffer
    __shared__ bf16 Bs[2][64 * 64];    //  8 KB per buffer

    const int tid  = threadIdx.x;
    const int wave = tid >> 6;
    const int lane = tid & 63;
    const int lr   = lane & 15;
    const int quad = lane >> 4;

    // ---- T1 XCD-panel-exclusive swizzle (bijective; nwg % 8 == 0) ----
    const int nx    = (mode == 0) ? (N_QKV / 64) : (D_MODEL / 64);
    const int bid   = blockIdx.x;
    const int chunk = gridDim.x >> 3;
    const int v     = (bid & 7) * chunk + (bid >> 3);
    const int m0 = (v / nx) * 128;
    const int n0 = (v % nx) * 64;

    const int wm = (wave >> 1) * 64;
    const int wn = (wave & 1) * 32;

    // W segment select (boundaries 64-aligned; whole 64-row tile inside one)
    const float* Wseg; int wrow;
    if      (n0 < D_MODEL)          { Wseg = W0; wrow = n0; }
    else if (n0 < D_MODEL + KV_DIM) { Wseg = W1; wrow = n0 - D_MODEL; }
    else                            { Wseg = W2; wrow = n0 - D_MODEL - KV_DIM; }

    // ---- staging geometry (swizzled slot; same layout as proven glds) ----
    const int cr8 = lane >> 3;                       // row within 8-row chunk
    const int cc  = ((lane & 7) ^ cr8) * 8;          // swizzled col (elems)
    const float* Ag = &A[(size_t)(m0 + cr8) * KDIM + cc];
    const float* Wg = &Wseg[(size_t)(wrow + cr8) * KDIM + cc];

    float4 ra[6][2];
#define LOADT(kk)                                                             \
    do {                                                                      \
        _Pragma("unroll")                                                     \
        for (int c = 0; c < 4; c++) {                                         \
            const float* p = Ag + (size_t)((wave * 4 + c) * 8) * KDIM + (kk); \
            ra[c][0] = *(const float4*)p;                                     \
            ra[c][1] = *(const float4*)(p + 4);                               \
        }                                                                     \
        _Pragma("unroll")                                                     \
        for (int c = 0; c < 2; c++) {                                         \
            const float* p = Wg + (size_t)((wave * 2 + c) * 8) * KDIM + (kk); \
            ra[4 + c][0] = *(const float4*)p;                                 \
            ra[4 + c][1] = *(const float4*)(p + 4);                           \
        }                                                                     \
    } while (0)

#define CVTW(buf)                                                             \
    do {                                                                      \
        _Pragma("unroll")                                                     \
        for (int c = 0; c < 4; c++)                                           \
            *(bf16x8*)&As[buf][(wave * 4 + c) * 512 + lane * 8] =             \
                cv8(ra[c][0], ra[c][1]);                                      \
        _Pragma("unroll")                                                     \
        for (int c = 0; c < 2; c++)                                           \
            *(bf16x8*)&Bs[buf][(wave * 2 + c) * 512 + lane * 8] =             \
                cv8(ra[4 + c][0], ra[4 + c][1]);                              \
    } while (0)

    // ---- fragment-read swizzled column offsets (lane-constant) ----
    const int ax0 = (quad ^ (lane & 7)) * 8;         // ks=0 col offset (elems)
    const int ax1 = ax0 ^ 32;                        // ks=1: col16 ^= 4

    floatx4 acc[4][2];
#pragma unroll
    for (int i = 0; i < 4; i++)
#pragma unroll
        for (int j = 0; j < 2; j++) acc[i][j] = (floatx4)(0.0f);

    // prologue: stage tile 0
    LOADT(0);
    CVTW(0);
    __syncthreads();

    int cur = 0;
    for (int k0 = 0; k0 < KDIM; k0 += 64) {
        const bool nxt = (k0 + 64 < KDIM);
        if (nxt) LOADT(k0 + 64);     // issue next-tile global loads early

        bf16x8 a0[4], a1[4], b0[2], b1[2];
#pragma unroll
        for (int mi = 0; mi < 4; mi++) {
            a0[mi] = *(const bf16x8*)&As[cur][(wm + mi * 16 + lr) * 64 + ax0];
            a1[mi] = *(const bf16x8*)&As[cur][(wm + mi * 16 + lr) * 64 + ax1];
        }
#pragma unroll
        for (int ni = 0; ni < 2; ni++) {
            b0[ni] = *(const bf16x8*)&Bs[cur][(wn + ni * 16 + lr) * 64 + ax0];
            b1[ni] = *(const bf16x8*)&Bs[cur][(wn + ni * 16 + lr) * 64 + ax1];
        }

#pragma unroll
        for (int mi = 0; mi < 4; mi++)
#pragma unroll
            for (int ni = 0; ni < 2; ni++) {
                acc[mi][ni] = __builtin_amdgcn_mfma_f32_16x16x32_bf16(
                    a0[mi], b0[ni], acc[mi][ni], 0, 0, 0);
                acc[mi][ni] = __builtin_amdgcn_mfma_f32_16x16x32_bf16(
                    a1[mi], b1[ni], acc[mi][ni], 0, 0, 0);
            }

        if (nxt) CVTW(cur ^ 1);      // cvt + ds_write next tile (other buffer)
        __syncthreads();             // writes visible; prev reads done
        cur ^= 1;
    }
#undef LOADT
#undef CVTW

    if (mode == 0) {
        if (n0 >= D_MODEL + KV_DIM) {
            // ---- V: store transposed into Vt[(bg*64+d)*SEQ_T + t] ----
            const int g  = (n0 - (D_MODEL + KV_DIM)) >> 6;   // 0..3
            const int b  = m0 >> 11;
            const int bg = b * 4 + g;
#pragma unroll
            for (int mi = 0; mi < 4; mi++) {
#pragma unroll
                for (int ni = 0; ni < 2; ni++) {
                    int d  = wn + ni * 16 + lr;
                    int t0 = (m0 & (SEQ_T - 1)) + wm + mi * 16 + quad * 4;
                    bf16x4 v;
#pragma unroll
                    for (int r = 0; r < 4; r++) v[r] = (bf16)acc[mi][ni][r];
                    *(bf16x4*)&Vt[((size_t)(bg * 64 + d)) * SEQ_T + t0] = v;
                }
            }
        } else {
            // ---- Q / K: RoPE epilogue ----
            bf16* out; int ld, coff; float sc;
            if (n0 < D_MODEL) { out = Cq; ld = D_MODEL; coff = n0; sc = QSCALE; }
            else              { out = Ck; ld = KV_DIM;  coff = n0 - D_MODEL; sc = 1.0f; }
            float inv[2];
            float sgn = (lr & 1) ? 1.0f : -1.0f;
#pragma unroll
            for (int ni = 0; ni < 2; ni++) {
                int ip = (wn + ni * 16 + lr) >> 1;      // pair index 0..31 within head
                inv[ni] = exp2f(-(float)ip * FREQ_C);
            }
#pragma unroll
            for (int mi = 0; mi < 4; mi++) {
#pragma unroll
                for (int r = 0; r < 4; r++) {
                    int row = m0 + wm + mi * 16 + quad * 4 + r;
                    float p = (float)pos[row & (SEQ_T - 1)];
#pragma unroll
                    for (int ni = 0; ni < 2; ni++) {
                        float v  = acc[mi][ni][r];
                        float vp = __shfl_xor(v, 1);
                        float ang = p * inv[ni];
                        float ss, cc2;
                        __sincosf(ang, &ss, &cc2);
                        v = v * cc2 + vp * ss * sgn;    // even: x1 c - x2 s ; odd: x1 s + x2 c
                        out[(size_t)row * ld + coff + wn + ni * 16 + lr] = (bf16)(v * sc);
                    }
                }
            }
        }
    } else {
#pragma unroll
        for (int mi = 0; mi < 4; mi++)
#pragma unroll
            for (int ni = 0; ni < 2; ni++)
#pragma unroll
                for (int r = 0; r < 4; r++) {
                    int row = m0 + wm + mi * 16 + quad * 4 + r;
                    int col = n0 + wn + ni * 16 + lr;
                    Co[(size_t)row * D_MODEL + col] = acc[mi][ni][r];
                }
    }
}

// ---------------------------------------------------------------------------
// GQA-fused MFMA flash attention, P-in-register + T14 async staging.
//   Swapped QK^T (mfma(kf,qf) -> S^T, P lane-local); key-permuted PV.
//   K/V tiles for step j0+64 are prefetched into registers right after the
//   current tile's LDS write, so global latency hides under QK/softmax/PV.
//   AO output is fp32 (feeds fp32-staged O-proj). LDS 20.7 KB.
// ---------------------------------------------------------------------------
__global__ __launch_bounds__(256, 3)
void attn_mfma(const bf16* __restrict__ Q, const bf16* __restrict__ K,
               const bf16* __restrict__ Vt_g, float* __restrict__ AO)
{
    const int ST = 72;
    __shared__ bf16 Ks[64 * ST];
    __shared__ bf16 Vt[80 * ST];        // row 64 = ones, 65-79 zeros

    const int tid  = threadIdx.x;
    const int wave = tid >> 6;
    const int lane = tid & 63;
    const int lr   = lane & 15;
    const int quad = lane >> 4;
    const int bg = blockIdx.y;
    const int b = bg >> 2, g = bg & 3;
    const int h = g * 4 + wave;
    const int q0 = blockIdx.x * 32;

    bf16x8 qf[2][2];
#pragma unroll
    for (int mi = 0; mi < 2; mi++)
#pragma unroll
        for (int ks = 0; ks < 2; ks++)
            qf[mi][ks] = *(const bf16x8*)
                &Q[((size_t)(b * SEQ_T + q0 + mi * 16 + lr)) * D_MODEL
                   + h * 64 + ks * 32 + quad * 8];

    for (int i = tid; i < 15 * ST; i += 256) Vt[65 * ST + i] = (bf16)0.0f;
    if (tid < ST) Vt[64 * ST + tid] = (bf16)(tid < 64 ? 1.0f : 0.0f);

    floatx4 o[2][5];
#pragma unroll
    for (int mi = 0; mi < 2; mi++)
#pragma unroll
        for (int nt = 0; nt < 5; nt++) o[mi][nt] = (floatx4)(0.0f);

    const int t0   = (q0 >= WINDOW) ? ((q0 - WINDOW) & ~63) : 0;
    const int last = q0 & ~63;

    // per-thread staging slots: i=0,1 -> c = tid + i*256, row c>>3, col (c&7)*8
    const int srow0 = tid >> 3,        scol0 = (tid & 7) * 8;
    const int srow1 = (tid + 256) >> 3, scol1 = ((tid + 256) & 7) * 8;

    bf16x8 kreg[2], vreg[2];
#define LOADKV(jn)                                                            \
    do {                                                                      \
        kreg[0] = *(const bf16x8*)&K[((size_t)(b * SEQ_T + (jn) + srow0)) * KV_DIM + g * 64 + scol0]; \
        vreg[0] = *(const bf16x8*)&Vt_g[((size_t)(bg * 64 + srow0)) * SEQ_T + (jn) + scol0];          \
        kreg[1] = *(const bf16x8*)&K[((size_t)(b * SEQ_T + (jn) + srow1)) * KV_DIM + g * 64 + scol1]; \
        vreg[1] = *(const bf16x8*)&Vt_g[((size_t)(bg * 64 + srow1)) * SEQ_T + (jn) + scol1];          \
    } while (0)

    LOADKV(t0);

    for (int j0 = t0; j0 <= last; j0 += 64) {
        const bool mC = (j0 == last);
        const bool mW = (q0 >= WINDOW) && (j0 == t0);
        __syncthreads();                      // prev compute done with LDS
        *(bf16x8*)&Ks[srow0 * ST + scol0] = kreg[0];
        *(bf16x8*)&Vt[srow0 * ST + scol0] = vreg[0];
        *(bf16x8*)&Ks[srow1 * ST + scol1] = kreg[1];
        *(bf16x8*)&Vt[srow1 * ST + scol1] = vreg[1];
        if (j0 + 64 <= last) LOADKV(j0 + 64); // prefetch next tile into regs
        __syncthreads();                      // LDS tile ready

        // ---- QK^T swapped: lane holds S[key=nt*16+quad*4+r][q=mi*16+lr] ----
        floatx4 s2[4][2];
#pragma unroll
        for (int nt = 0; nt < 4; nt++)
#pragma unroll
            for (int mi = 0; mi < 2; mi++) s2[nt][mi] = (floatx4)(0.0f);
#pragma unroll
        for (int ks = 0; ks < 2; ks++) {
#pragma unroll
            for (int nt = 0; nt < 4; nt++) {
                bf16x8 kf = *(const bf16x8*)&Ks[(nt * 16 + lr) * ST + ks * 32 + quad * 8];
                s2[nt][0] = __builtin_amdgcn_mfma_f32_16x16x32_bf16(kf, qf[0][ks], s2[nt][0], 0, 0, 0);
                s2[nt][1] = __builtin_amdgcn_mfma_f32_16x16x32_bf16(kf, qf[1][ks], s2[nt][1], 0, 0, 0);
            }
        }

        if (mC) {
#pragma unroll
            for (int nt = 0; nt < 4; nt++)
#pragma unroll
                for (int mi = 0; mi < 2; mi++) {
                    int qi_ = q0 + mi * 16 + lr;
#pragma unroll
                    for (int r = 0; r < 4; r++) {
                        int key = j0 + nt * 16 + quad * 4 + r;
                        s2[nt][mi][r] = (key <= qi_) ? s2[nt][mi][r] : -1e30f;
                    }
                }
        } else if (mW) {
#pragma unroll
            for (int nt = 0; nt < 4; nt++)
#pragma unroll
                for (int mi = 0; mi < 2; mi++) {
                    int qi_ = q0 + mi * 16 + lr;
#pragma unroll
                    for (int r = 0; r < 4; r++) {
                        int key = j0 + nt * 16 + quad * 4 + r;
                        s2[nt][mi][r] = (qi_ - key <= WINDOW) ? s2[nt][mi][r] : -1e30f;
                    }
                }
        }

        // ---- exp2 + lane-local pack into key-permuted A-frags ----
        bf16x8 pa[2][2];
#pragma unroll
        for (int mi = 0; mi < 2; mi++)
#pragma unroll
            for (int ks = 0; ks < 2; ks++)
#pragma unroll
                for (int r = 0; r < 4; r++) {
                    pa[mi][ks][r]     = (bf16)exp2f(s2[2 * ks][mi][r]);
                    pa[mi][ks][r + 4] = (bf16)exp2f(s2[2 * ks + 1][mi][r]);
                }

        // ---- PV with key-permuted B-frag (two b64 reads per vf) ----
#pragma unroll
        for (int ks = 0; ks < 2; ks++) {
#pragma unroll
            for (int nt = 0; nt < 5; nt++) {
                const bf16* vb = &Vt[(nt * 16 + lr) * ST + ks * 32 + quad * 4];
                bf16x4 vlo = *(const bf16x4*)vb;
                bf16x4 vhi = *(const bf16x4*)(vb + 16);
                bf16x8 vf = __builtin_shufflevector(vlo, vhi, 0, 1, 2, 3, 4, 5, 6, 7);
                o[0][nt] = __builtin_amdgcn_mfma_f32_16x16x32_bf16(pa[0][ks], vf, o[0][nt], 0, 0, 0);
                o[1][nt] = __builtin_amdgcn_mfma_f32_16x16x32_bf16(pa[1][ks], vf, o[1][nt], 0, 0, 0);
            }
        }
    }
#undef LOADKV

#pragma unroll
    for (int mi = 0; mi < 2; mi++)
#pragma unroll
        for (int r = 0; r < 4; r++) {
            float l = __shfl(o[mi][4][r], lane & 48);
            float invl = 1.0f / l;
            int row = q0 + mi * 16 + quad * 4 + r;
#pragma unroll
            for (int nt = 0; nt < 4; nt++)
                AO[((size_t)(b * SEQ_T + row)) * D_MODEL + h * 64 + nt * 16 + lr] =
                    o[mi][nt][r] * invl;
        }
}

// ---------------------------------------------------------------------------
extern "C" void kernel_launch(void* const* d_in, const int* in_sizes, int n_in,
                              void* d_out, int out_size, void* d_ws, size_t ws_size,
                              hipStream_t stream)
{
    const float* x  = (const float*)d_in[0];
    const float* WQ = (const float*)d_in[1];
    const float* WK = (const float*)d_in[2];
    const float* WV = (const float*)d_in[3];
    const float* WO = (const float*)d_in[4];
    const int*  pos = (const int*)d_in[5];

    // ws: Qw 8MB | Kw 2MB | Vt_g 2MB | AO fp32 16MB
    char* ws    = (char*)d_ws;
    bf16* Qw    = (bf16*)ws;
    bf16* Kw    = (bf16*)(ws + (size_t) 8 * 1024 * 1024);
    bf16* Vt_g  = (bf16*)(ws + (size_t)10 * 1024 * 1024);
    float* AOf  = (float*)(ws + (size_t)12 * 1024 * 1024);

    // fused QKV projection (fp32 sources) + RoPE epilogue + V-transpose
    // 1-D grid, XCD-panel-exclusive swizzle inside the kernel
    gemm_t64<<<(N_QKV / 64) * (M_ROWS / 128), 256, 0, stream>>>(
        x, WQ, WK, WV, Qw, Kw, Vt_g, nullptr, pos, 0);

    // GQA-fused attention (fp32 AO out)
    attn_mfma<<<dim3(SEQ_T / 32, BATCH * NUM_GROUPS), 256, 0, stream>>>(
        Qw, Kw, Vt_g, AOf);

    // output projection -> fp32 d_out
    gemm_t64<<<(D_MODEL / 64) * (M_ROWS / 128), 256, 0, stream>>>(
        AOf, WO, nullptr, nullptr, nullptr, nullptr, nullptr,
        (float*)d_out, pos, 1);
}